// Round 9
// baseline (291.452 us; speedup 1.0000x reference)
//
#include <hip/hip_runtime.h>
#include <math.h>

typedef unsigned short u16;
typedef __bf16 bf16x8 __attribute__((ext_vector_type(8)));
typedef float f32x4 __attribute__((ext_vector_type(4)));

#define NPOS 1156           // 34*34 padded positions
#define GSTR 1160           // Gpad/Apad2 row stride (elems)
#define GOFF (GSTR * 1156)  // per-batch elems = 1340960
#define YSTR 1032           // Ylin row stride (bf16)
#define YOFF (YSTR * 1026)  // per-batch Ylin elems
#define POS34(p) ((((p) >> 5) + 1) * 34 + ((p) & 31) + 1)

__device__ __constant__ const int kDiagOff[9] = {
    -35 * (GSTR + 1), -34 * (GSTR + 1), -33 * (GSTR + 1),
    -1 * (GSTR + 1),  0,                1 * (GSTR + 1),
    33 * (GSTR + 1),  34 * (GSTR + 1),  35 * (GSTR + 1)};

__device__ __forceinline__ u16 f2bf(float f) {
  unsigned int u = __builtin_bit_cast(unsigned int, f);
  return (u16)((u + 0x7FFFu + ((u >> 16) & 1u)) >> 16);
}
__device__ __forceinline__ float bf2f(u16 v) {
  unsigned int u = ((unsigned int)v) << 16;
  return __builtin_bit_cast(float, u);
}
__device__ __forceinline__ void gload16(const void* g, void* l) {
  __builtin_amdgcn_global_load_lds(
      (const __attribute__((address_space(1))) void*)g,
      (__attribute__((address_space(3))) void*)l, 16, 0, 0);
}
__device__ __forceinline__ int posOf(int p) { return POS34(p); }

__device__ __forceinline__ float wredmax(float v) {
#pragma unroll
  for (int m = 32; m; m >>= 1) v = fmaxf(v, __shfl_xor(v, m));
  return v;
}
__device__ __forceinline__ float wredsum(float v) {
#pragma unroll
  for (int m = 32; m; m >>= 1) v += __shfl_xor(v, m);
  return v;
}

// ---------------------------------------------------------------------------
// Border zeroing (replaces bulk memsets): only border elements are written.
// ---------------------------------------------------------------------------
__global__ __launch_bounds__(256) void zb_pre(
    float* __restrict__ Gpad, u16* __restrict__ Ylin,
    u16* __restrict__ xpad, u16* __restrict__ ypad) {
  int bi = blockIdx.x, tid = threadIdx.x;
  if (bi < 9248) {  // Gpad: 8 batches x 1156 rows
    int b = bi / 1156, r = bi - b * 1156;
    float* row = Gpad + (size_t)b * GOFF + (size_t)r * GSTR;
    int rm = r % 34;
    bool brow = (r < 34) || (r >= 1122) || (rm == 0) || (rm == 33);
    if (brow) {
      for (int c = tid; c < GSTR; c += 256) row[c] = 0.f;
    } else {
      for (int c = tid; c < GSTR; c += 256) {
        int cm = c % 34;
        if (c < 34 || c >= 1122 || cm == 0 || cm == 33) row[c] = 0.f;
      }
    }
    return;
  }
  bi -= 9248;
  if (bi < 8208) {  // Ylin: 8 x 1026 rows
    int b = bi / 1026, r = bi - b * 1026;
    u16* row = Ylin + (size_t)b * YOFF + (size_t)r * YSTR;
    if (r == 0 || r == 1025) {
      for (int c = tid; c < YSTR; c += 256) row[c] = 0;
    } else if (tid < 8) {
      row[tid == 0 ? 0 : 1024 + tid] = 0;
    }
    return;
  }
  bi -= 8208;  // xpad then ypad: 2 x 8 x 1156 positions
  int arr = bi / 9248;
  bi -= arr * 9248;
  int b = bi / 1156, p = bi - b * 1156;
  int pm = p % 34;
  bool bp = (p < 34) || (p >= 1122) || (pm == 0) || (pm == 33);
  if (!bp) return;
  u16* dst = (arr ? ypad : xpad) + ((size_t)b * NPOS + p) * 256;
  dst[tid] = 0;
}

__global__ __launch_bounds__(256) void zb_apad(u16* __restrict__ Apad2) {
  int bi = blockIdx.x, tid = threadIdx.x;
  int b = bi / 1156, r = bi - b * 1156;
  u16* row = Apad2 + (size_t)b * GOFF + (size_t)r * GSTR;
  int rm = r % 34;
  bool brow = (r < 34) || (r >= 1122) || (rm == 0) || (rm == 33);
  if (brow) {
    for (int c = tid; c < GSTR; c += 256) row[c] = 0;
  } else {
    for (int c = tid; c < GSTR; c += 256) {
      int cm = c % 34;
      if (c < 34 || c >= 1122 || cm == 0 || cm == 33) row[c] = 0;
    }
  }
}

// ---------------------------------------------------------------------------
// cast x -> xpad [b][34][34][256] bf16 and xT [b][256][1024] bf16
// ---------------------------------------------------------------------------
__global__ __launch_bounds__(256) void cast_x(
    const float* __restrict__ x, u16* __restrict__ xpad, u16* __restrict__ xT) {
  int blk = blockIdx.x;  // b*32 + h
  int b = blk >> 5, h = blk & 31;
  __shared__ u16 T[256][33];
  const float* xrow = x + ((size_t)b * 1024 + h * 32) * 256;
  int tid = threadIdx.x;
  for (int idx = tid; idx < 8192; idx += 256) {
    int w = idx >> 8, c = idx & 255;
    u16 v = f2bf(xrow[(size_t)w * 256 + c]);
    T[c][w] = v;
    xpad[((size_t)b * NPOS + (h + 1) * 34 + (w + 1)) * 256 + c] = v;
  }
  __syncthreads();
  int c = tid;
  unsigned int* dp = (unsigned int*)(xT + ((size_t)(b * 256 + c)) * 1024 + h * 32);
  const unsigned int* sp = (const unsigned int*)&T[c][0];
#pragma unroll
  for (int u = 0; u < 16; ++u) dp[u] = sp[u];
}

// weight transpose: src f32 [K][256] -> dst bf16 [256][K]
__global__ __launch_bounds__(256) void wtrans(
    const float* __restrict__ src, u16* __restrict__ dst, int K) {
  int k0 = blockIdx.x * 32;
  __shared__ u16 T[256][34];
  int tid = threadIdx.x;
  for (int idx = tid; idx < 8192; idx += 256) {
    int kr = idx >> 8, c = idx & 255;
    T[c][kr] = f2bf(src[(size_t)(k0 + kr) * 256 + c]);
  }
  __syncthreads();
  int c = tid;
  unsigned int* dp = (unsigned int*)(dst + (size_t)c * K + k0);
  const unsigned int* sp = (const unsigned int*)&T[c][0];
#pragma unroll
  for (int u = 0; u < 16; ++u) dp[u] = sp[u];
}

// ---------------------------------------------------------------------------
// Gbase[p,l] = sum_c x[p,c]*x[l,c] -> Gpad (spatially padded f32, zero border)
// ---------------------------------------------------------------------------
__global__ __launch_bounds__(256) void gram_base(
    const u16* __restrict__ xpad, float* __restrict__ Gpad) {
  const int b = blockIdx.z;
  const int m0 = blockIdx.x << 7;
  const int n0 = blockIdx.y << 7;
  const u16* xb = xpad + (size_t)b * NPOS * 256;
  __shared__ __align__(16) u16 As[128 * 64];
  __shared__ __align__(16) u16 Bs[128 * 64];
  const int tid = threadIdx.x;
  const int lane = tid & 63;
  const int wave = tid >> 6;
  const int wm = wave >> 1, wn = wave & 1;
  const int srow = lane >> 3;
  const int cswz = ((lane & 7) ^ srow) << 3;
  int pa[4], pb[4];
#pragma unroll
  for (int i = 0; i < 4; ++i) {
    pa[i] = posOf(m0 + wave * 32 + i * 8 + srow);
    pb[i] = posOf(n0 + wave * 32 + i * 8 + srow);
  }
  int aidx[4][2], bidx[4][2];
#pragma unroll
  for (int f = 0; f < 4; ++f)
#pragma unroll
    for (int ks = 0; ks < 2; ++ks) {
      int ra = wm * 64 + f * 16 + (lane & 15);
      int rb = wn * 64 + f * 16 + (lane & 15);
      int k16 = ks * 4 + (lane >> 4);
      aidx[f][ks] = ra * 64 + ((k16 ^ (ra & 7)) << 3);
      bidx[f][ks] = rb * 64 + ((k16 ^ (rb & 7)) << 3);
    }
  f32x4 acc[4][4] = {};
  for (int c0 = 0; c0 < 256; c0 += 64) {
    __syncthreads();
#pragma unroll
    for (int i = 0; i < 4; ++i) {
      gload16(xb + (size_t)pa[i] * 256 + c0 + cswz, &As[(wave * 32 + i * 8) * 64]);
      gload16(xb + (size_t)pb[i] * 256 + c0 + cswz, &Bs[(wave * 32 + i * 8) * 64]);
    }
    __syncthreads();
#pragma unroll
    for (int ks = 0; ks < 2; ++ks) {
      bf16x8 a[4], bb[4];
#pragma unroll
      for (int f = 0; f < 4; ++f) a[f] = *(const bf16x8*)(As + aidx[f][ks]);
#pragma unroll
      for (int f = 0; f < 4; ++f) bb[f] = *(const bf16x8*)(Bs + bidx[f][ks]);
#pragma unroll
      for (int mi = 0; mi < 4; ++mi)
#pragma unroll
        for (int ni = 0; ni < 4; ++ni)
          acc[mi][ni] = __builtin_amdgcn_mfma_f32_16x16x32_bf16(a[mi], bb[ni], acc[mi][ni], 0, 0, 0);
    }
  }
  float* Gb = Gpad + (size_t)b * GOFF;
  const int r0 = (lane >> 4) << 2;
  const int cb0 = n0 + wn * 64 + (lane & 15);
#pragma unroll
  for (int mi = 0; mi < 4; ++mi) {
    int row = m0 + wm * 64 + mi * 16 + r0;
    int rp = POS34(row);  // rows row..row+3 contiguous in pos-space
#pragma unroll
    for (int ni = 0; ni < 4; ++ni) {
      int cp = POS34(cb0 + ni * 16);
#pragma unroll
      for (int r = 0; r < 4; ++r)
        Gb[(size_t)(rp + r) * GSTR + cp] = acc[mi][ni][r];
    }
  }
}

// ---------------------------------------------------------------------------
// invn from 9-tap diagonal of Gpad; mm; ones tail
// ---------------------------------------------------------------------------
__global__ __launch_bounds__(256) void norm_mm(
    const float* __restrict__ Gpad, const float* __restrict__ mask,
    float* __restrict__ invn, float* __restrict__ mm, float* __restrict__ ones_out) {
  int idx = blockIdx.x * 256 + threadIdx.x;
  int b = idx >> 10, l = idx & 1023;
  const float* Gb = Gpad + (size_t)b * GOFF;
  size_t dbase = (size_t)POS34(l) * (GSTR + 1);
  float d = 0.f;
#pragma unroll
  for (int t = 0; t < 9; ++t) d += Gb[dbase + kDiagOff[t]];
  invn[idx] = 1.0f / fmaxf(sqrtf(d), 1e-4f);
  int lh = l >> 5, lw = l & 31;
  float s = 0.f;
  for (int dh = -1; dh <= 1; ++dh)
    for (int dw = -1; dw <= 1; ++dw) {
      int hh = lh + dh, wv = lw + dw;
      if (hh >= 0 && hh < 32 && wv >= 0 && wv < 32) s += mask[b * 1024 + hh * 32 + wv];
    }
  mm[idx] = ((s / 9.0f) == 1.0f) ? 1.0f : 0.0f;
  ones_out[idx] = 1.0f;
}

// ---------------------------------------------------------------------------
// Ylin[p+1][l+1] (bf16) = invn[l] * sum_t Gpad[ppos+d_t][lpos+d_t]
// ---------------------------------------------------------------------------
__global__ __launch_bounds__(256) void patch_norm_p(
    const float* __restrict__ Gpad, const float* __restrict__ invn,
    u16* __restrict__ Ylin) {
  const int b = blockIdx.y;
  const int p0 = blockIdx.x << 2;
  const float* Gb = Gpad + (size_t)b * GOFF;
  u16* Yb = Ylin + (size_t)b * YOFF;
  const int tid = threadIdx.x;
  const int l0 = tid << 2;
  const int lp0 = POS34(l0);
  const float4 iv = *(const float4*)(invn + (b << 10) + l0);
#pragma unroll
  for (int r = 0; r < 4; ++r) {
    int p = p0 + r;
    int base = POS34(p) * GSTR + lp0;
    float v[9][4];
#pragma unroll
    for (int t = 0; t < 9; ++t) {
      const float* q = Gb + (base + kDiagOff[t]);
      v[t][0] = q[0]; v[t][1] = q[1]; v[t][2] = q[2]; v[t][3] = q[3];
    }
    float s0 = 0.f, s1 = 0.f, s2 = 0.f, s3 = 0.f;
#pragma unroll
    for (int t = 0; t < 9; ++t) { s0 += v[t][0]; s1 += v[t][1]; s2 += v[t][2]; s3 += v[t][3]; }
    u16* yw = Yb + (size_t)(p + 1) * YSTR + l0 + 1;
    yw[0] = f2bf(s0 * iv.x); yw[1] = f2bf(s1 * iv.y);
    yw[2] = f2bf(s2 * iv.z); yw[3] = f2bf(s3 * iv.w);
  }
}

// ---------------------------------------------------------------------------
// Fused diag-fuse + mask + softmax, 4 rows/block (1 wave per row).
// Interior blocks cache the 18 needed Ylin rows (3 bands of 6) in LDS.
// Wave-shuffle reductions (no barrier trees). Border blocks: global path.
// ---------------------------------------------------------------------------
#define CSTR 1032

__device__ __forceinline__ float z1p(const u16* __restrict__ Yb, int r, int c) {
  size_t a = (size_t)(r + 1) * YSTR + (c + 1);
  return bf2f(Yb[a]) + bf2f(Yb[a - (YSTR + 1)]) + bf2f(Yb[a + (YSTR + 1)]);
}

__global__ __launch_bounds__(256) void fuse_softmax_band(
    const u16* __restrict__ Ylin, const float* __restrict__ mm,
    u16* __restrict__ Apad2) {
  const int bi = blockIdx.x;  // 2048
  const int b = bi >> 8;
  const int i0 = (bi & 255) << 2;
  const u16* Yb = Ylin + (size_t)b * YOFF;
  const float* mmb = mm + (b << 10);
  const int tid = threadIdx.x;
  const int w = tid >> 6;
  const int lane = tid & 63;
  const int i = i0 + w;
  __shared__ __align__(16) u16 cache[18 * CSTR];
  const bool interior = (i0 >= 32) && (i0 <= 988);
  float logit[16];
  float mmv[16];
  float lmax = -3.0e38f;
  if (interior) {
    // bands (padded rows): upper i0-32.. , center i0.. , lower i0+32.. (6 each)
    for (int ch = tid; ch < 18 * 129; ch += 256) {
      int k = ch / 129;
      int c8 = (ch - k * 129) << 3;
      int g = (k < 6) ? (i0 - 32 + k) : (k < 12) ? (i0 + k - 6) : (i0 + 32 + k - 12);
      gload16(Yb + (size_t)g * YSTR + c8, cache + ch * 8);
    }
    __syncthreads();
    const u16* cu = cache + w * CSTR;
    const u16* cc = cache + (w + 6) * CSTR;
    const u16* cl = cache + (w + 12) * CSTR;
#define Z1C(base, c) (bf2f((base)[(c)]) + bf2f((base)[CSTR + (c) + 1]) + bf2f((base)[2 * CSTR + (c) + 2]))
#pragma unroll
    for (int q = 0; q < 16; ++q) {
      int j = lane + (q << 6);
      int sj = ((j & 31) << 5) | (j >> 5);
      float S = Z1C(cc, j);
      if (sj >= 1) {
        int col = (((sj - 1) & 31) << 5) | ((sj - 1) >> 5);
        S += Z1C(cu, col);
      }
      if (sj <= 1022) {
        int col = (((sj + 1) & 31) << 5) | ((sj + 1) >> 5);
        S += Z1C(cl, col);
      }
      mmv[q] = mmb[j];
      float lg = S * mmv[q] * 10.0f;
      logit[q] = lg;
      lmax = fmaxf(lmax, lg);
    }
  } else {
    const int si = ((i & 31) << 5) | (i >> 5);
    const int rm = (si >= 1) ? ((((si - 1) & 31) << 5) | ((si - 1) >> 5)) : -1;
    const int rp = (si <= 1022) ? ((((si + 1) & 31) << 5) | ((si + 1) >> 5)) : -1;
#pragma unroll
    for (int q = 0; q < 16; ++q) {
      int j = lane + (q << 6);
      int sj = ((j & 31) << 5) | (j >> 5);
      float S = z1p(Yb, i, j);
      if (rm >= 0 && sj >= 1) {
        int col = (((sj - 1) & 31) << 5) | ((sj - 1) >> 5);
        S += z1p(Yb, rm, col);
      }
      if (rp >= 0 && sj <= 1022) {
        int col = (((sj + 1) & 31) << 5) | ((sj + 1) >> 5);
        S += z1p(Yb, rp, col);
      }
      mmv[q] = mmb[j];
      float lg = S * mmv[q] * 10.0f;
      logit[q] = lg;
      lmax = fmaxf(lmax, lg);
    }
  }
  lmax = wredmax(lmax);
  float lsum = 0.f;
#pragma unroll
  for (int q = 0; q < 16; ++q) { logit[q] = expf(logit[q] - lmax); lsum += logit[q]; }
  lsum = wredsum(lsum);
  float inv = 1.0f / lsum;
  u16* Ap = Apad2 + (size_t)b * GOFF + (size_t)POS34(i) * GSTR;
#pragma unroll
  for (int q = 0; q < 16; ++q) {
    int j = lane + (q << 6);
    Ap[POS34(j)] = f2bf(mmv[q] * logit[q] * inv);
  }
}

// ---------------------------------------------------------------------------
// Afuse[q][l] (dense bf16) = sum_t Apad2[qpos-d_t][lpos-d_t]  (unconditional)
// ---------------------------------------------------------------------------
__global__ __launch_bounds__(256) void afuse_p(
    const u16* __restrict__ Apad2, u16* __restrict__ Afuse) {
  const int b = blockIdx.y;
  const int q0 = blockIdx.x << 2;
  const u16* Ab = Apad2 + (size_t)b * GOFF;
  u16* Fb = Afuse + ((size_t)b << 20);
  const int tid = threadIdx.x;
  const int l0 = tid << 2;
  const int lp0 = POS34(l0);
#pragma unroll
  for (int r = 0; r < 4; ++r) {
    int q = q0 + r;
    int base = POS34(q) * GSTR + lp0;
    float v[9][4];
#pragma unroll
    for (int t = 0; t < 9; ++t) {
      const u16* p = Ab + (base - kDiagOff[t]);
      v[t][0] = bf2f(p[0]); v[t][1] = bf2f(p[1]);
      v[t][2] = bf2f(p[2]); v[t][3] = bf2f(p[3]);
    }
    float s0 = 0.f, s1 = 0.f, s2 = 0.f, s3 = 0.f;
#pragma unroll
    for (int t = 0; t < 9; ++t) { s0 += v[t][0]; s1 += v[t][1]; s2 += v[t][2]; s3 += v[t][3]; }
    u16* fw = Fb + (size_t)q * 1024 + l0;
    fw[0] = f2bf(s0); fw[1] = f2bf(s1); fw[2] = f2bf(s2); fw[3] = f2bf(s3);
  }
}

// ---------------------------------------------------------------------------
// paste GEMM: ypad[q,c] = sum_l Afuse[q,l] * x[l,c]; M64 x N64, K=1024
// ---------------------------------------------------------------------------
__global__ __launch_bounds__(256) void paste_gemm(
    const u16* __restrict__ Afuse, const u16* __restrict__ xT, u16* __restrict__ ypad) {
  const int bm0 = blockIdx.x << 6;
  const int b = bm0 >> 10;
  const int q0 = bm0 & 1023;
  const int n0 = blockIdx.y << 6;
  const u16* Ab = Afuse + ((size_t)b << 20);
  const u16* xTb = xT + ((size_t)b << 18);
  __shared__ __align__(16) u16 As[64 * 64];
  __shared__ __align__(16) u16 Bs[64 * 64];
  const int tid = threadIdx.x;
  const int lane = tid & 63;
  const int wave = tid >> 6;
  const int wm = wave >> 1, wn = wave & 1;
  const int srow = lane >> 3;
  const int cswz = ((lane & 7) ^ srow) << 3;
  int aidx[2][2], bidx[2][2];
#pragma unroll
  for (int ks = 0; ks < 2; ++ks) {
    int k16 = ks * 4 + (lane >> 4);
#pragma unroll
    for (int f = 0; f < 2; ++f) {
      int ra = wm * 32 + f * 16 + (lane & 15);
      aidx[f][ks] = ra * 64 + ((k16 ^ (ra & 7)) << 3);
      int rb = wn * 32 + f * 16 + (lane & 15);
      bidx[f][ks] = rb * 64 + ((k16 ^ (rb & 7)) << 3);
    }
  }
  f32x4 acc[2][2] = {};
  for (int l0 = 0; l0 < 1024; l0 += 64) {
    __syncthreads();
#pragma unroll
    for (int i = 0; i < 2; ++i) {
      int ar = wave * 16 + i * 8 + srow;
      gload16(Ab + (size_t)(q0 + ar) * 1024 + l0 + cswz, &As[ar * 64]);
      gload16(xTb + (size_t)(n0 + ar) * 1024 + l0 + cswz, &Bs[ar * 64]);
    }
    __syncthreads();
#pragma unroll
    for (int ks = 0; ks < 2; ++ks) {
      bf16x8 a[2], bb[2];
#pragma unroll
      for (int f = 0; f < 2; ++f) a[f] = *(const bf16x8*)(As + aidx[f][ks]);
#pragma unroll
      for (int f = 0; f < 2; ++f) bb[f] = *(const bf16x8*)(Bs + bidx[f][ks]);
#pragma unroll
      for (int mi = 0; mi < 2; ++mi)
#pragma unroll
        for (int ni = 0; ni < 2; ++ni)
          acc[mi][ni] = __builtin_amdgcn_mfma_f32_16x16x32_bf16(a[mi], bb[ni], acc[mi][ni], 0, 0, 0);
    }
  }
  u16* yb = ypad + (size_t)b * NPOS * 256;
  const int r0 = (lane >> 4) << 2;
#pragma unroll
  for (int mi = 0; mi < 2; ++mi) {
    int qb = q0 + wm * 32 + mi * 16 + r0;
#pragma unroll
    for (int ni = 0; ni < 2; ++ni) {
      int c = n0 + wn * 32 + ni * 16 + (lane & 15);
#pragma unroll
      for (int r = 0; r < 4; ++r)
        yb[(size_t)posOf(qb + r) * 256 + c] = f2bf(acc[mi][ni][r]);
    }
  }
}

// ---------------------------------------------------------------------------
// conv_split: one 3x3x512 conv (w0T or w2T by blockIdx.z)
// M128 x N64 tiles, grid (64, 4, 2) = 512 blocks = 2/CU, 24KB LDS
// ---------------------------------------------------------------------------
__global__ __launch_bounds__(256) void conv_split(
    const u16* __restrict__ ypad, const u16* __restrict__ xpad,
    const u16* __restrict__ w0T, const u16* __restrict__ w2T,
    float* __restrict__ c0buf, float* __restrict__ c2buf) {
  const int m0 = blockIdx.x << 7;
  const int b = m0 >> 10;
  const int q0 = m0 & 1023;
  const int sel = blockIdx.z;
  const int n0 = blockIdx.y << 6;
  const u16* wT = sel ? w2T : w0T;
  float* dst = sel ? c2buf : c0buf;
  const u16* yb = ypad + (size_t)b * NPOS * 256;
  const u16* xb = xpad + (size_t)b * NPOS * 256;
  __shared__ __align__(16) u16 As[128 * 64];
  __shared__ __align__(16) u16 Bs[64 * 64];
  const int tid = threadIdx.x;
  const int lane = tid & 63;
  const int wave = tid >> 6;
  const int wm = wave >> 1, wn = wave & 1;
  const int srow = lane >> 3;
  const int cswz = ((lane & 7) ^ srow) << 3;
  int posA[4];
#pragma unroll
  for (int i = 0; i < 4; ++i) posA[i] = posOf(q0 + wave * 32 + i * 8 + srow);
  const u16* wrow[2];
#pragma unroll
  for (int i = 0; i < 2; ++i)
    wrow[i] = wT + (size_t)(n0 + wave * 16 + i * 8 + srow) * 4608 + cswz;
  int aidx[4][2], bidx[2][2];
#pragma unroll
  for (int ks = 0; ks < 2; ++ks) {
    int k16 = ks * 4 + (lane >> 4);
#pragma unroll
    for (int f = 0; f < 4; ++f) {
      int ra = wm * 64 + f * 16 + (lane & 15);
      aidx[f][ks] = ra * 64 + ((k16 ^ (ra & 7)) << 3);
    }
#pragma unroll
    for (int f = 0; f < 2; ++f) {
      int rb = wn * 32 + f * 16 + (lane & 15);
      bidx[f][ks] = rb * 64 + ((k16 ^ (rb & 7)) << 3);
    }
  }
  f32x4 acc[4][2] = {};
  for (int kt = 0; kt < 72; ++kt) {
    const int s = kt >> 3;
    const int c0k = (kt & 7) << 6;
    const u16* basep = (c0k < 256) ? yb : xb;
    const int coff = c0k & 255;
    const int dpos = (s / 3 - 1) * 34 + (s % 3 - 1);
    __syncthreads();
#pragma unroll
    for (int i = 0; i < 4; ++i)
      gload16(basep + (size_t)(posA[i] + dpos) * 256 + coff + cswz,
              &As[(wave * 32 + i * 8) * 64]);
#pragma unroll
    for (int i = 0; i < 2; ++i)
      gload16(wrow[i] + (kt << 6), &Bs[(wave * 16 + i * 8) * 64]);
    __syncthreads();
#pragma unroll
    for (int ks = 0; ks < 2; ++ks) {
      bf16x8 a[4], bb[2];
#pragma unroll
      for (int f = 0; f < 4; ++f) a[f] = *(const bf16x8*)(As + aidx[f][ks]);
#pragma unroll
      for (int f = 0; f < 2; ++f) bb[f] = *(const bf16x8*)(Bs + bidx[f][ks]);
#pragma unroll
      for (int mi = 0; mi < 4; ++mi)
#pragma unroll
        for (int ni = 0; ni < 2; ++ni)
          acc[mi][ni] = __builtin_amdgcn_mfma_f32_16x16x32_bf16(a[mi], bb[ni], acc[mi][ni], 0, 0, 0);
    }
  }
  const int r0 = (lane >> 4) << 2;
#pragma unroll
  for (int mi = 0; mi < 4; ++mi) {
    int m = m0 + wm * 64 + mi * 16 + r0;
#pragma unroll
    for (int ni = 0; ni < 2; ++ni) {
      int co = n0 + wn * 32 + ni * 16 + (lane & 15);
#pragma unroll
      for (int r = 0; r < 4; ++r)
        dst[(size_t)(m + r) * 256 + co] = acc[mi][ni][r];
    }
  }
}

// ---------------------------------------------------------------------------
// conv1: 1x1x512 conv of ycat (center tap), K=512, grid (128,4)
// ---------------------------------------------------------------------------
__global__ __launch_bounds__(256) void conv1_gemm(
    const u16* __restrict__ ypad, const u16* __restrict__ xpad,
    const u16* __restrict__ w1T, float* __restrict__ c1buf) {
  const int m0 = blockIdx.x << 6;
  const int b = m0 >> 10;
  const int q0 = m0 & 1023;
  const int n0 = blockIdx.y << 6;
  const u16* yb = ypad + (size_t)b * NPOS * 256;
  const u16* xb = xpad + (size_t)b * NPOS * 256;
  __shared__ __align__(16) u16 As[64 * 64];
  __shared__ __align__(16) u16 Bs[64 * 64];
  const int tid = threadIdx.x;
  const int lane = tid & 63;
  const int wave = tid >> 6;
  const int wm = wave >> 1, wn = wave & 1;
  const int srow = lane >> 3;
  const int cswz = ((lane & 7) ^ srow) << 3;
  int posA[2];
#pragma unroll
  for (int i = 0; i < 2; ++i) posA[i] = posOf(q0 + wave * 16 + i * 8 + srow);
  int aidx[2][2], bidx[2][2];
#pragma unroll
  for (int ks = 0; ks < 2; ++ks) {
    int k16 = ks * 4 + (lane >> 4);
#pragma unroll
    for (int f = 0; f < 2; ++f) {
      int ra = wm * 32 + f * 16 + (lane & 15);
      aidx[f][ks] = ra * 64 + ((k16 ^ (ra & 7)) << 3);
      int rb = wn * 32 + f * 16 + (lane & 15);
      bidx[f][ks] = rb * 64 + ((k16 ^ (rb & 7)) << 3);
    }
  }
  f32x4 acc[2][2] = {};
  for (int kt = 0; kt < 8; ++kt) {
    const int c0k = kt << 6;
    const u16* basep = (c0k < 256) ? yb : xb;
    const int coff = c0k & 255;
    __syncthreads();
#pragma unroll
    for (int i = 0; i < 2; ++i) {
      int ar = wave * 16 + i * 8 + srow;
      gload16(basep + (size_t)posA[i] * 256 + coff + cswz, &As[ar * 64]);
      gload16(w1T + (size_t)(n0 + ar) * 512 + c0k + cswz, &Bs[ar * 64]);
    }
    __syncthreads();
#pragma unroll
    for (int ks = 0; ks < 2; ++ks) {
      bf16x8 a[2], bb[2];
#pragma unroll
      for (int f = 0; f < 2; ++f) a[f] = *(const bf16x8*)(As + aidx[f][ks]);
#pragma unroll
      for (int f = 0; f < 2; ++f) bb[f] = *(const bf16x8*)(Bs + bidx[f][ks]);
#pragma unroll
      for (int mi = 0; mi < 2; ++mi)
#pragma unroll
        for (int ni = 0; ni < 2; ++ni)
          acc[mi][ni] = __builtin_amdgcn_mfma_f32_16x16x32_bf16(a[mi], bb[ni], acc[mi][ni], 0, 0, 0);
    }
  }
  const int r0 = (lane >> 4) << 2;
#pragma unroll
  for (int mi = 0; mi < 2; ++mi) {
    int m = m0 + wm * 32 + mi * 16 + r0;
#pragma unroll
    for (int ni = 0; ni < 2; ++ni) {
      int co = n0 + wn * 32 + ni * 16 + (lane & 15);
#pragma unroll
      for (int r = 0; r < 4; ++r)
        c1buf[(size_t)(m + r) * 256 + co] = acc[mi][ni][r];
    }
  }
}

// ---------------------------------------------------------------------------
// gate: out = 0.5*(sig(c1+b1)+sig(c2+b2))*(c0+b0)
// ---------------------------------------------------------------------------
__global__ __launch_bounds__(256) void gate_out(
    const float* __restrict__ c0buf, const float* __restrict__ c1buf,
    const float* __restrict__ c2buf, const float* __restrict__ b0,
    const float* __restrict__ b1, const float* __restrict__ b2,
    float* __restrict__ out) {
  size_t i4 = ((size_t)blockIdx.x * 256 + threadIdx.x) * 4;
  int co = (int)(i4 & 255);
  float4 v0 = *(const float4*)(c0buf + i4);
  float4 v1 = *(const float4*)(c1buf + i4);
  float4 v2 = *(const float4*)(c2buf + i4);
  float4 q0 = *(const float4*)(b0 + co);
  float4 q1 = *(const float4*)(b1 + co);
  float4 q2 = *(const float4*)(b2 + co);
  float4 o;
  const float* pv0 = (const float*)&v0; const float* pv1 = (const float*)&v1;
  const float* pv2 = (const float*)&v2; const float* pq0 = (const float*)&q0;
  const float* pq1 = (const float*)&q1; const float* pq2 = (const float*)&q2;
  float* po = (float*)&o;
#pragma unroll
  for (int j = 0; j < 4; ++j) {
    float g1 = 1.f / (1.f + expf(-(pv1[j] + pq1[j])));
    float g2 = 1.f / (1.f + expf(-(pv2[j] + pq2[j])));
    po[j] = 0.5f * (g1 + g2) * (pv0[j] + pq0[j]);
  }
  *(float4*)(out + i4) = o;
}

// ---------------------------------------------------------------------------

extern "C" void kernel_launch(void* const* d_in, const int* in_sizes, int n_in,
                              void* d_out, int out_size, void* d_ws, size_t ws_size,
                              hipStream_t stream) {
  const float* x = (const float*)d_in[0];
  const float* mask = (const float*)d_in[1];
  const float* conv_w = (const float*)d_in[2];
  const float* conv_b = (const float*)d_in[3];
  const float* conv1_w = (const float*)d_in[4];
  const float* conv1_b = (const float*)d_in[5];
  const float* conv2_w = (const float*)d_in[6];
  const float* conv2_b = (const float*)d_in[7];
  float* out = (float*)d_out;
  char* wsb = (char*)d_ws;

  // workspace layout (bytes)
  float* Gpad  = (float*)(wsb + 0);          // 42,910,720 f32 (dead after patch_norm)
  u16* Apad2   = (u16*)(wsb + 0);            // 21,455,360 bf16 (aliases Gpad; dead after afuse)
  float* c0buf = (float*)(wsb + 0);          //  8,388,608 (after Apad2 dead)
  float* c2buf = (float*)(wsb + 8388608);    //  8,388,608
  float* c1buf = (float*)(wsb + 16777216);   //  8,388,608
  u16* Ylin    = (u16*)(wsb + 42910720);     // 16,941,312 bf16 (dead after fuse_softmax)
  u16* Afuse   = (u16*)(wsb + 42910720);     // 16,777,216 (aliases dead Ylin)
  u16* xpad    = (u16*)(wsb + 59852032);     //  4,734,976
  u16* ypad    = (u16*)(wsb + 64587008);     //  4,734,976
  u16* xT      = (u16*)(wsb + 69321984);     //  4,194,304
  u16* w0T     = (u16*)(wsb + 73516288);     //  2,359,296
  u16* w2T     = (u16*)(wsb + 75875584);     //  2,359,296
  u16* w1T     = (u16*)(wsb + 78234880);     //    262,144
  float* invn  = (float*)(wsb + 78497024);
  float* mmb   = (float*)(wsb + 78529792);

  zb_pre<<<35952, 256, 0, stream>>>(Gpad, Ylin, xpad, ypad);
  cast_x<<<256, 256, 0, stream>>>(x, xpad, xT);
  wtrans<<<144, 256, 0, stream>>>(conv_w, w0T, 4608);
  wtrans<<<144, 256, 0, stream>>>(conv2_w, w2T, 4608);
  wtrans<<<16, 256, 0, stream>>>(conv1_w, w1T, 512);

  gram_base<<<dim3(8, 8, 8), 256, 0, stream>>>(xpad, Gpad);
  norm_mm<<<32, 256, 0, stream>>>(Gpad, mask, invn, mmb, out + 2097152);
  patch_norm_p<<<dim3(256, 8), 256, 0, stream>>>(Gpad, invn, Ylin);
  zb_apad<<<9248, 256, 0, stream>>>(Apad2);
  fuse_softmax_band<<<2048, 256, 0, stream>>>(Ylin, mmb, Apad2);
  afuse_p<<<dim3(256, 8), 256, 0, stream>>>(Apad2, Afuse);
  paste_gemm<<<dim3(128, 4), 256, 0, stream>>>(Afuse, xT, ypad);
  conv1_gemm<<<dim3(128, 4), 256, 0, stream>>>(ypad, xpad, w1T, c1buf);
  conv_split<<<dim3(64, 4, 2), 256, 0, stream>>>(ypad, xpad, w0T, w2T, c0buf, c2buf);
  gate_out<<<2048, 256, 0, stream>>>(c0buf, c1buf, c2buf, conv_b, conv1_b, conv2_b, out);
}

// Round 10
// 279.944 us; speedup vs baseline: 1.0411x; 1.0411x over previous
//
#include <hip/hip_runtime.h>
#include <math.h>

typedef unsigned short u16;
typedef __bf16 bf16x8 __attribute__((ext_vector_type(8)));
typedef float f32x4 __attribute__((ext_vector_type(4)));

#define NPOS 1156           // 34*34 padded positions
#define GSTR 1160           // Gpad/Apad2 row stride (elems)
#define GOFF (GSTR * 1156)  // per-batch elems = 1340960
#define YSTR 1032           // Ylin row stride (bf16)
#define YOFF (YSTR * 1026)  // per-batch Ylin elems
#define POS34(p) ((((p) >> 5) + 1) * 34 + ((p) & 31) + 1)

__device__ __constant__ const int kDiagOff[9] = {
    -35 * (GSTR + 1), -34 * (GSTR + 1), -33 * (GSTR + 1),
    -1 * (GSTR + 1),  0,                1 * (GSTR + 1),
    33 * (GSTR + 1),  34 * (GSTR + 1),  35 * (GSTR + 1)};

__device__ __forceinline__ u16 f2bf(float f) {
  unsigned int u = __builtin_bit_cast(unsigned int, f);
  return (u16)((u + 0x7FFFu + ((u >> 16) & 1u)) >> 16);
}
__device__ __forceinline__ float bf2f(u16 v) {
  unsigned int u = ((unsigned int)v) << 16;
  return __builtin_bit_cast(float, u);
}
__device__ __forceinline__ void gload16(const void* g, void* l) {
  __builtin_amdgcn_global_load_lds(
      (const __attribute__((address_space(1))) void*)g,
      (__attribute__((address_space(3))) void*)l, 16, 0, 0);
}
__device__ __forceinline__ int posOf(int p) { return POS34(p); }

__device__ __forceinline__ float wredmax(float v) {
#pragma unroll
  for (int m = 32; m; m >>= 1) v = fmaxf(v, __shfl_xor(v, m));
  return v;
}
__device__ __forceinline__ float wredsum(float v) {
#pragma unroll
  for (int m = 32; m; m >>= 1) v += __shfl_xor(v, m);
  return v;
}

// ---------------------------------------------------------------------------
// Border zeroing (replaces bulk memsets)
// ---------------------------------------------------------------------------
__global__ __launch_bounds__(256) void zb_pre(
    float* __restrict__ Gpad, u16* __restrict__ Ylin,
    u16* __restrict__ xpad, u16* __restrict__ ypad) {
  int bi = blockIdx.x, tid = threadIdx.x;
  if (bi < 9248) {  // Gpad: 8 batches x 1156 rows
    int b = bi / 1156, r = bi - b * 1156;
    float* row = Gpad + (size_t)b * GOFF + (size_t)r * GSTR;
    int rm = r % 34;
    bool brow = (r < 34) || (r >= 1122) || (rm == 0) || (rm == 33);
    if (brow) {
      for (int c = tid; c < GSTR; c += 256) row[c] = 0.f;
    } else {
      for (int c = tid; c < GSTR; c += 256) {
        int cm = c % 34;
        if (c < 34 || c >= 1122 || cm == 0 || cm == 33) row[c] = 0.f;
      }
    }
    return;
  }
  bi -= 9248;
  if (bi < 8208) {  // Ylin: 8 x 1026 rows
    int b = bi / 1026, r = bi - b * 1026;
    u16* row = Ylin + (size_t)b * YOFF + (size_t)r * YSTR;
    if (r == 0 || r == 1025) {
      for (int c = tid; c < YSTR; c += 256) row[c] = 0;
    } else if (tid < 8) {
      row[tid == 0 ? 0 : 1024 + tid] = 0;
    }
    return;
  }
  bi -= 8208;  // xpad then ypad: 2 x 8 x 1156 positions
  int arr = bi / 9248;
  bi -= arr * 9248;
  int b = bi / 1156, p = bi - b * 1156;
  int pm = p % 34;
  bool bp = (p < 34) || (p >= 1122) || (pm == 0) || (pm == 33);
  if (!bp) return;
  u16* dst = (arr ? ypad : xpad) + ((size_t)b * NPOS + p) * 256;
  dst[tid] = 0;
}

__global__ __launch_bounds__(256) void zb_apad(u16* __restrict__ Apad2) {
  int bi = blockIdx.x, tid = threadIdx.x;
  int b = bi / 1156, r = bi - b * 1156;
  u16* row = Apad2 + (size_t)b * GOFF + (size_t)r * GSTR;
  int rm = r % 34;
  bool brow = (r < 34) || (r >= 1122) || (rm == 0) || (rm == 33);
  if (brow) {
    for (int c = tid; c < GSTR; c += 256) row[c] = 0;
  } else {
    for (int c = tid; c < GSTR; c += 256) {
      int cm = c % 34;
      if (c < 34 || c >= 1122 || cm == 0 || cm == 33) row[c] = 0;
    }
  }
}

// ---------------------------------------------------------------------------
// cast x -> xpad [b][34][34][256] bf16 and xT [b][256][1024] bf16
// ---------------------------------------------------------------------------
__global__ __launch_bounds__(256) void cast_x(
    const float* __restrict__ x, u16* __restrict__ xpad, u16* __restrict__ xT) {
  int blk = blockIdx.x;  // b*32 + h
  int b = blk >> 5, h = blk & 31;
  __shared__ u16 T[256][33];
  const float* xrow = x + ((size_t)b * 1024 + h * 32) * 256;
  int tid = threadIdx.x;
  for (int idx = tid; idx < 8192; idx += 256) {
    int w = idx >> 8, c = idx & 255;
    u16 v = f2bf(xrow[(size_t)w * 256 + c]);
    T[c][w] = v;
    xpad[((size_t)b * NPOS + (h + 1) * 34 + (w + 1)) * 256 + c] = v;
  }
  __syncthreads();
  int c = tid;
  unsigned int* dp = (unsigned int*)(xT + ((size_t)(b * 256 + c)) * 1024 + h * 32);
  const unsigned int* sp = (const unsigned int*)&T[c][0];
#pragma unroll
  for (int u = 0; u < 16; ++u) dp[u] = sp[u];
}

// weight transpose: src f32 [K][256] -> dst bf16 [256][K]
__global__ __launch_bounds__(256) void wtrans(
    const float* __restrict__ src, u16* __restrict__ dst, int K) {
  int k0 = blockIdx.x * 32;
  __shared__ u16 T[256][34];
  int tid = threadIdx.x;
  for (int idx = tid; idx < 8192; idx += 256) {
    int kr = idx >> 8, c = idx & 255;
    T[c][kr] = f2bf(src[(size_t)(k0 + kr) * 256 + c]);
  }
  __syncthreads();
  int c = tid;
  unsigned int* dp = (unsigned int*)(dst + (size_t)c * K + k0);
  const unsigned int* sp = (const unsigned int*)&T[c][0];
#pragma unroll
  for (int u = 0; u < 16; ++u) dp[u] = sp[u];
}

// ---------------------------------------------------------------------------
// Gbase[p,l] = sum_c x[p,c]*x[l,c] -> Gpad (f32, zero border). XCD-chunked.
// ---------------------------------------------------------------------------
__global__ __launch_bounds__(256) void gram_base(
    const u16* __restrict__ xpad, float* __restrict__ Gpad) {
  int lid = blockIdx.x + (blockIdx.y << 3) + (blockIdx.z << 6);  // (8,8,8)
  int swz = ((lid & 7) << 6) + (lid >> 3);
  const int b = swz >> 6;
  const int m0 = (swz & 7) << 7;
  const int n0 = ((swz >> 3) & 7) << 7;
  const u16* xb = xpad + (size_t)b * NPOS * 256;
  __shared__ __align__(16) u16 As[128 * 64];
  __shared__ __align__(16) u16 Bs[128 * 64];
  const int tid = threadIdx.x;
  const int lane = tid & 63;
  const int wave = tid >> 6;
  const int wm = wave >> 1, wn = wave & 1;
  const int srow = lane >> 3;
  const int cswz = ((lane & 7) ^ srow) << 3;
  int pa[4], pb[4];
#pragma unroll
  for (int i = 0; i < 4; ++i) {
    pa[i] = posOf(m0 + wave * 32 + i * 8 + srow);
    pb[i] = posOf(n0 + wave * 32 + i * 8 + srow);
  }
  int aidx[4][2], bidx[4][2];
#pragma unroll
  for (int f = 0; f < 4; ++f)
#pragma unroll
    for (int ks = 0; ks < 2; ++ks) {
      int ra = wm * 64 + f * 16 + (lane & 15);
      int rb = wn * 64 + f * 16 + (lane & 15);
      int k16 = ks * 4 + (lane >> 4);
      aidx[f][ks] = ra * 64 + ((k16 ^ (ra & 7)) << 3);
      bidx[f][ks] = rb * 64 + ((k16 ^ (rb & 7)) << 3);
    }
  f32x4 acc[4][4] = {};
  for (int c0 = 0; c0 < 256; c0 += 64) {
    __syncthreads();
#pragma unroll
    for (int i = 0; i < 4; ++i) {
      gload16(xb + (size_t)pa[i] * 256 + c0 + cswz, &As[(wave * 32 + i * 8) * 64]);
      gload16(xb + (size_t)pb[i] * 256 + c0 + cswz, &Bs[(wave * 32 + i * 8) * 64]);
    }
    __syncthreads();
#pragma unroll
    for (int ks = 0; ks < 2; ++ks) {
      bf16x8 a[4], bb[4];
#pragma unroll
      for (int f = 0; f < 4; ++f) a[f] = *(const bf16x8*)(As + aidx[f][ks]);
#pragma unroll
      for (int f = 0; f < 4; ++f) bb[f] = *(const bf16x8*)(Bs + bidx[f][ks]);
#pragma unroll
      for (int mi = 0; mi < 4; ++mi)
#pragma unroll
        for (int ni = 0; ni < 4; ++ni)
          acc[mi][ni] = __builtin_amdgcn_mfma_f32_16x16x32_bf16(a[mi], bb[ni], acc[mi][ni], 0, 0, 0);
    }
  }
  float* Gb = Gpad + (size_t)b * GOFF;
  const int r0 = (lane >> 4) << 2;
  const int cb0 = n0 + wn * 64 + (lane & 15);
#pragma unroll
  for (int mi = 0; mi < 4; ++mi) {
    int row = m0 + wm * 64 + mi * 16 + r0;
    int rp = POS34(row);
#pragma unroll
    for (int ni = 0; ni < 4; ++ni) {
      int cp = POS34(cb0 + ni * 16);
#pragma unroll
      for (int r = 0; r < 4; ++r)
        Gb[(size_t)(rp + r) * GSTR + cp] = acc[mi][ni][r];
    }
  }
}

// ---------------------------------------------------------------------------
// invn from 9-tap diagonal of Gpad; mm; ones tail
// ---------------------------------------------------------------------------
__global__ __launch_bounds__(256) void norm_mm(
    const float* __restrict__ Gpad, const float* __restrict__ mask,
    float* __restrict__ invn, float* __restrict__ mm, float* __restrict__ ones_out) {
  int idx = blockIdx.x * 256 + threadIdx.x;
  int b = idx >> 10, l = idx & 1023;
  const float* Gb = Gpad + (size_t)b * GOFF;
  size_t dbase = (size_t)POS34(l) * (GSTR + 1);
  float d = 0.f;
#pragma unroll
  for (int t = 0; t < 9; ++t) d += Gb[dbase + kDiagOff[t]];
  invn[idx] = 1.0f / fmaxf(sqrtf(d), 1e-4f);
  int lh = l >> 5, lw = l & 31;
  float s = 0.f;
  for (int dh = -1; dh <= 1; ++dh)
    for (int dw = -1; dw <= 1; ++dw) {
      int hh = lh + dh, wv = lw + dw;
      if (hh >= 0 && hh < 32 && wv >= 0 && wv < 32) s += mask[b * 1024 + hh * 32 + wv];
    }
  mm[idx] = ((s / 9.0f) == 1.0f) ? 1.0f : 0.0f;
  ones_out[idx] = 1.0f;
}

// ---------------------------------------------------------------------------
// Ylin[p+1][l+1] (bf16) = invn[l] * sum_t Gpad[ppos+d_t][lpos+d_t]
// XCD-chunked: each XCD walks one batch contiguously -> taps hit L2.
// ---------------------------------------------------------------------------
__global__ __launch_bounds__(256) void patch_norm_p(
    const float* __restrict__ Gpad, const float* __restrict__ invn,
    u16* __restrict__ Ylin) {
  int lid = blockIdx.x + (blockIdx.y << 8);  // (256, 8)
  int swz = ((lid & 7) << 8) + (lid >> 3);
  const int b = swz >> 8;
  const int p0 = (swz & 255) << 2;
  const float* Gb = Gpad + (size_t)b * GOFF;
  u16* Yb = Ylin + (size_t)b * YOFF;
  const int tid = threadIdx.x;
  const int l0 = tid << 2;
  const int lp0 = POS34(l0);
  const float4 iv = *(const float4*)(invn + (b << 10) + l0);
#pragma unroll
  for (int r = 0; r < 4; ++r) {
    int p = p0 + r;
    int base = POS34(p) * GSTR + lp0;
    float v[9][4];
#pragma unroll
    for (int t = 0; t < 9; ++t) {
      const float* q = Gb + (base + kDiagOff[t]);
      v[t][0] = q[0]; v[t][1] = q[1]; v[t][2] = q[2]; v[t][3] = q[3];
    }
    float s0 = 0.f, s1 = 0.f, s2 = 0.f, s3 = 0.f;
#pragma unroll
    for (int t = 0; t < 9; ++t) { s0 += v[t][0]; s1 += v[t][1]; s2 += v[t][2]; s3 += v[t][3]; }
    u16* yw = Yb + (size_t)(p + 1) * YSTR + l0 + 1;
    yw[0] = f2bf(s0 * iv.x); yw[1] = f2bf(s1 * iv.y);
    yw[2] = f2bf(s2 * iv.z); yw[3] = f2bf(s3 * iv.w);
  }
}

// ---------------------------------------------------------------------------
// Fused diag-fuse + mask + softmax, 4 rows/block (1 wave per row), banded LDS.
// ---------------------------------------------------------------------------
#define CSTR 1032

__device__ __forceinline__ float z1p(const u16* __restrict__ Yb, int r, int c) {
  size_t a = (size_t)(r + 1) * YSTR + (c + 1);
  return bf2f(Yb[a]) + bf2f(Yb[a - (YSTR + 1)]) + bf2f(Yb[a + (YSTR + 1)]);
}

__global__ __launch_bounds__(256) void fuse_softmax_band(
    const u16* __restrict__ Ylin, const float* __restrict__ mm,
    u16* __restrict__ Apad2) {
  int lid = blockIdx.x;  // 2048
  int swz = ((lid & 7) << 8) + (lid >> 3);
  const int b = swz >> 8;
  const int i0 = (swz & 255) << 2;
  const u16* Yb = Ylin + (size_t)b * YOFF;
  const float* mmb = mm + (b << 10);
  const int tid = threadIdx.x;
  const int w = tid >> 6;
  const int lane = tid & 63;
  const int i = i0 + w;
  __shared__ __align__(16) u16 cache[18 * CSTR];
  const bool interior = (i0 >= 32) && (i0 <= 988);
  float logit[16];
  float mmv[16];
  float lmax = -3.0e38f;
  if (interior) {
    for (int ch = tid; ch < 18 * 129; ch += 256) {
      int k = ch / 129;
      int c8 = (ch - k * 129) << 3;
      int g = (k < 6) ? (i0 - 32 + k) : (k < 12) ? (i0 + k - 6) : (i0 + 32 + k - 12);
      gload16(Yb + (size_t)g * YSTR + c8, cache + ch * 8);
    }
    __syncthreads();
    const u16* cu = cache + w * CSTR;
    const u16* cc = cache + (w + 6) * CSTR;
    const u16* cl = cache + (w + 12) * CSTR;
#define Z1C(base, c) (bf2f((base)[(c)]) + bf2f((base)[CSTR + (c) + 1]) + bf2f((base)[2 * CSTR + (c) + 2]))
#pragma unroll
    for (int q = 0; q < 16; ++q) {
      int j = lane + (q << 6);
      int sj = ((j & 31) << 5) | (j >> 5);
      float S = Z1C(cc, j);
      if (sj >= 1) {
        int col = (((sj - 1) & 31) << 5) | ((sj - 1) >> 5);
        S += Z1C(cu, col);
      }
      if (sj <= 1022) {
        int col = (((sj + 1) & 31) << 5) | ((sj + 1) >> 5);
        S += Z1C(cl, col);
      }
      mmv[q] = mmb[j];
      float lg = S * mmv[q] * 10.0f;
      logit[q] = lg;
      lmax = fmaxf(lmax, lg);
    }
  } else {
    const int si = ((i & 31) << 5) | (i >> 5);
    const int rm = (si >= 1) ? ((((si - 1) & 31) << 5) | ((si - 1) >> 5)) : -1;
    const int rp = (si <= 1022) ? ((((si + 1) & 31) << 5) | ((si + 1) >> 5)) : -1;
#pragma unroll
    for (int q = 0; q < 16; ++q) {
      int j = lane + (q << 6);
      int sj = ((j & 31) << 5) | (j >> 5);
      float S = z1p(Yb, i, j);
      if (rm >= 0 && sj >= 1) {
        int col = (((sj - 1) & 31) << 5) | ((sj - 1) >> 5);
        S += z1p(Yb, rm, col);
      }
      if (rp >= 0 && sj <= 1022) {
        int col = (((sj + 1) & 31) << 5) | ((sj + 1) >> 5);
        S += z1p(Yb, rp, col);
      }
      mmv[q] = mmb[j];
      float lg = S * mmv[q] * 10.0f;
      logit[q] = lg;
      lmax = fmaxf(lmax, lg);
    }
  }
  lmax = wredmax(lmax);
  float lsum = 0.f;
#pragma unroll
  for (int q = 0; q < 16; ++q) { logit[q] = expf(logit[q] - lmax); lsum += logit[q]; }
  lsum = wredsum(lsum);
  float inv = 1.0f / lsum;
  u16* Ap = Apad2 + (size_t)b * GOFF + (size_t)POS34(i) * GSTR;
#pragma unroll
  for (int q = 0; q < 16; ++q) {
    int j = lane + (q << 6);
    Ap[POS34(j)] = f2bf(mmv[q] * logit[q] * inv);
  }
}

// ---------------------------------------------------------------------------
// Afuse[q][l] (dense bf16) = sum_t Apad2[qpos-d_t][lpos-d_t]. XCD-chunked.
// ---------------------------------------------------------------------------
__global__ __launch_bounds__(256) void afuse_p(
    const u16* __restrict__ Apad2, u16* __restrict__ Afuse) {
  int lid = blockIdx.x + (blockIdx.y << 8);  // (256, 8)
  int swz = ((lid & 7) << 8) + (lid >> 3);
  const int b = swz >> 8;
  const int q0 = (swz & 255) << 2;
  const u16* Ab = Apad2 + (size_t)b * GOFF;
  u16* Fb = Afuse + ((size_t)b << 20);
  const int tid = threadIdx.x;
  const int l0 = tid << 2;
  const int lp0 = POS34(l0);
#pragma unroll
  for (int r = 0; r < 4; ++r) {
    int q = q0 + r;
    int base = POS34(q) * GSTR + lp0;
    float v[9][4];
#pragma unroll
    for (int t = 0; t < 9; ++t) {
      const u16* p = Ab + (base - kDiagOff[t]);
      v[t][0] = bf2f(p[0]); v[t][1] = bf2f(p[1]);
      v[t][2] = bf2f(p[2]); v[t][3] = bf2f(p[3]);
    }
    float s0 = 0.f, s1 = 0.f, s2 = 0.f, s3 = 0.f;
#pragma unroll
    for (int t = 0; t < 9; ++t) { s0 += v[t][0]; s1 += v[t][1]; s2 += v[t][2]; s3 += v[t][3]; }
    u16* fw = Fb + (size_t)q * 1024 + l0;
    fw[0] = f2bf(s0); fw[1] = f2bf(s1); fw[2] = f2bf(s2); fw[3] = f2bf(s3);
  }
}

// ---------------------------------------------------------------------------
// paste GEMM: ypad[q,c] = sum_l Afuse[q,l] * x[l,c]; M64 x N64, K=1024
// ---------------------------------------------------------------------------
__global__ __launch_bounds__(256) void paste_gemm(
    const u16* __restrict__ Afuse, const u16* __restrict__ xT, u16* __restrict__ ypad) {
  int lid = blockIdx.x + (blockIdx.y << 7);  // (128, 4)
  int swz = ((lid & 7) << 6) + (lid >> 3);
  const int bm0 = (swz & 127) << 6;
  const int b = bm0 >> 10;
  const int q0 = bm0 & 1023;
  const int n0 = (swz >> 7) << 6;
  const u16* Ab = Afuse + ((size_t)b << 20);
  const u16* xTb = xT + ((size_t)b << 18);
  __shared__ __align__(16) u16 As[64 * 64];
  __shared__ __align__(16) u16 Bs[64 * 64];
  const int tid = threadIdx.x;
  const int lane = tid & 63;
  const int wave = tid >> 6;
  const int wm = wave >> 1, wn = wave & 1;
  const int srow = lane >> 3;
  const int cswz = ((lane & 7) ^ srow) << 3;
  int aidx[2][2], bidx[2][2];
#pragma unroll
  for (int ks = 0; ks < 2; ++ks) {
    int k16 = ks * 4 + (lane >> 4);
#pragma unroll
    for (int f = 0; f < 2; ++f) {
      int ra = wm * 32 + f * 16 + (lane & 15);
      aidx[f][ks] = ra * 64 + ((k16 ^ (ra & 7)) << 3);
      int rb = wn * 32 + f * 16 + (lane & 15);
      bidx[f][ks] = rb * 64 + ((k16 ^ (rb & 7)) << 3);
    }
  }
  f32x4 acc[2][2] = {};
  for (int l0 = 0; l0 < 1024; l0 += 64) {
    __syncthreads();
#pragma unroll
    for (int i = 0; i < 2; ++i) {
      int ar = wave * 16 + i * 8 + srow;
      gload16(Ab + (size_t)(q0 + ar) * 1024 + l0 + cswz, &As[ar * 64]);
      gload16(xTb + (size_t)(n0 + ar) * 1024 + l0 + cswz, &Bs[ar * 64]);
    }
    __syncthreads();
#pragma unroll
    for (int ks = 0; ks < 2; ++ks) {
      bf16x8 a[2], bb[2];
#pragma unroll
      for (int f = 0; f < 2; ++f) a[f] = *(const bf16x8*)(As + aidx[f][ks]);
#pragma unroll
      for (int f = 0; f < 2; ++f) bb[f] = *(const bf16x8*)(Bs + bidx[f][ks]);
#pragma unroll
      for (int mi = 0; mi < 2; ++mi)
#pragma unroll
        for (int ni = 0; ni < 2; ++ni)
          acc[mi][ni] = __builtin_amdgcn_mfma_f32_16x16x32_bf16(a[mi], bb[ni], acc[mi][ni], 0, 0, 0);
    }
  }
  u16* yb = ypad + (size_t)b * NPOS * 256;
  const int r0 = (lane >> 4) << 2;
#pragma unroll
  for (int mi = 0; mi < 2; ++mi) {
    int qb = q0 + wm * 32 + mi * 16 + r0;
#pragma unroll
    for (int ni = 0; ni < 2; ++ni) {
      int c = n0 + wn * 32 + ni * 16 + (lane & 15);
#pragma unroll
      for (int r = 0; r < 4; ++r)
        yb[(size_t)posOf(qb + r) * 256 + c] = f2bf(acc[mi][ni][r]);
    }
  }
}

// ---------------------------------------------------------------------------
// final fused: acc0=conv_w (9 taps), acc1=conv1_w (center), acc2=conv2_w
// out = 0.5*(sig(acc1+b1)+sig(acc2+b2))*(acc0+b0). M64 x N64, grid (128,4).
// XCD-chunked: each XCD owns 64 m-tiles of one n-panel -> weights L2-resident.
// ---------------------------------------------------------------------------
__global__ __launch_bounds__(256) void final_fused(
    const u16* __restrict__ ypad, const u16* __restrict__ xpad,
    const u16* __restrict__ w0T, const u16* __restrict__ w1T,
    const u16* __restrict__ w2T,
    const float* __restrict__ b0, const float* __restrict__ b1,
    const float* __restrict__ b2, float* __restrict__ out) {
  int lid = blockIdx.x + (blockIdx.y << 7);  // (128, 4)
  int swz = ((lid & 7) << 6) + (lid >> 3);
  const int m0 = (swz & 127) << 6;
  const int b = m0 >> 10;
  const int q0 = m0 & 1023;
  const int n0 = (swz >> 7) << 6;
  const u16* yb = ypad + (size_t)b * NPOS * 256;
  const u16* xb = xpad + (size_t)b * NPOS * 256;
  __shared__ __align__(16) u16 As[64 * 64];
  __shared__ __align__(16) u16 B0s[64 * 64];
  __shared__ __align__(16) u16 B1s[64 * 64];
  __shared__ __align__(16) u16 B2s[64 * 64];
  const int tid = threadIdx.x;
  const int lane = tid & 63;
  const int wave = tid >> 6;
  const int wm = wave >> 1, wn = wave & 1;
  const int srow = lane >> 3;
  const int cswz = ((lane & 7) ^ srow) << 3;
  int posA[2];
#pragma unroll
  for (int i = 0; i < 2; ++i) posA[i] = posOf(q0 + wave * 16 + i * 8 + srow);
  int aidx[2][2], bidx[2][2];
#pragma unroll
  for (int ks = 0; ks < 2; ++ks) {
    int k16 = ks * 4 + (lane >> 4);
#pragma unroll
    for (int f = 0; f < 2; ++f) {
      int ra = wm * 32 + f * 16 + (lane & 15);
      aidx[f][ks] = ra * 64 + ((k16 ^ (ra & 7)) << 3);
      int rb = wn * 32 + f * 16 + (lane & 15);
      bidx[f][ks] = rb * 64 + ((k16 ^ (rb & 7)) << 3);
    }
  }
  f32x4 acc0[2][2] = {}, acc1[2][2] = {}, acc2[2][2] = {};
  for (int kt = 0; kt < 72; ++kt) {
    const int s = kt >> 3;
    const int c0k = (kt & 7) << 6;
    const u16* basep = (c0k < 256) ? yb : xb;
    const int coff = c0k & 255;
    const int dpos = (s / 3 - 1) * 34 + (s % 3 - 1);
    __syncthreads();
#pragma unroll
    for (int i = 0; i < 2; ++i) {
      int ar = wave * 16 + i * 8 + srow;
      gload16(basep + (size_t)(posA[i] + dpos) * 256 + coff + cswz, &As[ar * 64]);
      size_t krow = (size_t)(n0 + ar) * 4608 + (kt << 6) + cswz;
      gload16(w0T + krow, &B0s[ar * 64]);
      gload16(w2T + krow, &B2s[ar * 64]);
      if (s == 4)
        gload16(w1T + (size_t)(n0 + ar) * 512 + c0k + cswz, &B1s[ar * 64]);
    }
    __syncthreads();
#pragma unroll
    for (int ks = 0; ks < 2; ++ks) {
      bf16x8 a[2], v0[2], v2[2];
#pragma unroll
      for (int f = 0; f < 2; ++f) a[f] = *(const bf16x8*)(As + aidx[f][ks]);
#pragma unroll
      for (int f = 0; f < 2; ++f) v0[f] = *(const bf16x8*)(B0s + bidx[f][ks]);
#pragma unroll
      for (int f = 0; f < 2; ++f) v2[f] = *(const bf16x8*)(B2s + bidx[f][ks]);
#pragma unroll
      for (int mi = 0; mi < 2; ++mi)
#pragma unroll
        for (int ni = 0; ni < 2; ++ni) {
          acc0[mi][ni] = __builtin_amdgcn_mfma_f32_16x16x32_bf16(a[mi], v0[ni], acc0[mi][ni], 0, 0, 0);
          acc2[mi][ni] = __builtin_amdgcn_mfma_f32_16x16x32_bf16(a[mi], v2[ni], acc2[mi][ni], 0, 0, 0);
        }
      if (s == 4) {
        bf16x8 v1[2];
#pragma unroll
        for (int f = 0; f < 2; ++f) v1[f] = *(const bf16x8*)(B1s + bidx[f][ks]);
#pragma unroll
        for (int mi = 0; mi < 2; ++mi)
#pragma unroll
          for (int ni = 0; ni < 2; ++ni)
            acc1[mi][ni] = __builtin_amdgcn_mfma_f32_16x16x32_bf16(a[mi], v1[ni], acc1[mi][ni], 0, 0, 0);
      }
    }
  }
  const int r0 = (lane >> 4) << 2;
#pragma unroll
  for (int ni = 0; ni < 2; ++ni) {
    int co = n0 + wn * 32 + ni * 16 + (lane & 15);
    float q0b = b0[co], q1b = b1[co], q2b = b2[co];
#pragma unroll
    for (int mi = 0; mi < 2; ++mi) {
      int m = m0 + wm * 32 + mi * 16 + r0;
#pragma unroll
      for (int r = 0; r < 4; ++r) {
        float g1 = 1.f / (1.f + expf(-(acc1[mi][ni][r] + q1b)));
        float g2 = 1.f / (1.f + expf(-(acc2[mi][ni][r] + q2b)));
        out[(size_t)(m + r) * 256 + co] = 0.5f * (g1 + g2) * (acc0[mi][ni][r] + q0b);
      }
    }
  }
}

// ---------------------------------------------------------------------------

extern "C" void kernel_launch(void* const* d_in, const int* in_sizes, int n_in,
                              void* d_out, int out_size, void* d_ws, size_t ws_size,
                              hipStream_t stream) {
  const float* x = (const float*)d_in[0];
  const float* mask = (const float*)d_in[1];
  const float* conv_w = (const float*)d_in[2];
  const float* conv_b = (const float*)d_in[3];
  const float* conv1_w = (const float*)d_in[4];
  const float* conv1_b = (const float*)d_in[5];
  const float* conv2_w = (const float*)d_in[6];
  const float* conv2_b = (const float*)d_in[7];
  float* out = (float*)d_out;
  char* wsb = (char*)d_ws;

  // workspace layout (bytes)
  float* Gpad  = (float*)(wsb + 0);          // 42,910,720 f32 (dead after patch_norm)
  u16* Apad2   = (u16*)(wsb + 0);            // 21,455,360 bf16 (aliases Gpad)
  u16* Ylin    = (u16*)(wsb + 42910720);     // 16,941,312 bf16 (dead after fuse)
  u16* Afuse   = (u16*)(wsb + 42910720);     // 16,777,216 (aliases dead Ylin)
  u16* xpad    = (u16*)(wsb + 59852032);     //  4,734,976
  u16* ypad    = (u16*)(wsb + 64587008);     //  4,734,976
  u16* xT      = (u16*)(wsb + 69321984);     //  4,194,304
  u16* w0T     = (u16*)(wsb + 73516288);     //  2,359,296
  u16* w2T     = (u16*)(wsb + 75875584);     //  2,359,296
  u16* w1T     = (u16*)(wsb + 78234880);     //    262,144
  float* invn  = (float*)(wsb + 78497024);
  float* mmb   = (float*)(wsb + 78529792);

  zb_pre<<<35952, 256, 0, stream>>>(Gpad, Ylin, xpad, ypad);
  cast_x<<<256, 256, 0, stream>>>(x, xpad, xT);
  wtrans<<<144, 256, 0, stream>>>(conv_w, w0T, 4608);
  wtrans<<<144, 256, 0, stream>>>(conv2_w, w2T, 4608);
  wtrans<<<16, 256, 0, stream>>>(conv1_w, w1T, 512);

  gram_base<<<dim3(8, 8, 8), 256, 0, stream>>>(xpad, Gpad);
  norm_mm<<<32, 256, 0, stream>>>(Gpad, mask, invn, mmb, out + 2097152);
  patch_norm_p<<<dim3(256, 8), 256, 0, stream>>>(Gpad, invn, Ylin);
  zb_apad<<<9248, 256, 0, stream>>>(Apad2);
  fuse_softmax_band<<<2048, 256, 0, stream>>>(Ylin, mmb, Apad2);
  afuse_p<<<dim3(256, 8), 256, 0, stream>>>(Apad2, Afuse);
  paste_gemm<<<dim3(128, 4), 256, 0, stream>>>(Afuse, xT, ypad);
  final_fused<<<dim3(128, 4), 256, 0, stream>>>(ypad, xpad, w0T, w1T, w2T,
                                                conv_b, conv1_b, conv2_b, out);
}